// Round 8
// baseline (785.322 us; speedup 1.0000x reference)
//
#include <hip/hip_runtime.h>
#include <hip/hip_bf16.h>
#include <hip/hip_cooperative_groups.h>

namespace cg = cooperative_groups;

#define N_NODES 50000
#define N_EDGES 800000
#define DIN 256
#define DHID 128
#define DOUT 128
#define NBUCK 196     // buckets = dst >> 8
#define EPB 3125      // edges per partition (256*3125 = 800000 exact)
#define G1TILES 391   // ceil(50000/128) gemm1 tiles (4 waves x 32 rows)
#define HTP 136       // LDS ht row pitch in shorts (272B, 16B-aligned)

typedef __attribute__((ext_vector_type(8))) short bf16x8;
typedef __attribute__((ext_vector_type(4))) float f32x4;

__device__ inline unsigned short f2b(float f) {
    __hip_bfloat16 b = __float2bfloat16(f);
    return *reinterpret_cast<unsigned short*>(&b);
}

// ================= single cooperative mega-kernel =================
// 256 blocks x 1024 threads = 1 block/CU (co-resident). Phases separated by
// grid.sync(); each phase's algorithm identical to the multi-dispatch version
// proven at 182-184us (R4/R6). __threadfence() before each sync for cross-XCD
// L2 visibility (G16).
__global__ __launch_bounds__(1024, 4) void mega_kernel(
    const float* __restrict__ x,
    const int* __restrict__ ei,
    const float* __restrict__ W1,
    const float* __restrict__ att_src,
    const float* __restrict__ att_dst,
    const float* __restrict__ W2,
    unsigned short* __restrict__ W1t,
    unsigned short* __restrict__ W2t,
    int* __restrict__ blockHistT,
    int* __restrict__ matrixScan,
    unsigned short* __restrict__ hb,
    float* __restrict__ es,
    float* __restrict__ ed,
    int2* __restrict__ binned,
    int2* __restrict__ sortedSW,
    int* __restrict__ offset,
    int* __restrict__ count,
    float* __restrict__ out)
{
    cg::grid_group grid = cg::this_grid();
    __shared__ __align__(16) char smem[18432];
    const int blk = blockIdx.x;
    const int tid = threadIdx.x;

    // ===== Phase A: weight transpose+cast (fragment-ordered) + edge bucket hist =====
    if (blk < 48) {                             // 48*1024 = 49152 = 32768 + 16384
        int i = blk * 1024 + tid;
        if (i < DIN * DHID) {                   // W1: n=out channel, k=in channel
            int n = i >> 8, k = i & 255;
            int kt = k >> 5, q = (k >> 3) & 3, e = k & 7;
            int t = n >> 4, m = n & 15;
            W1t[(((kt * 8 + t) * 64) + (q * 16 + m)) * 8 + e] = f2b(W1[k * DHID + n]);
        } else {
            int j = i - DIN * DHID;
            int n = j >> 7, k = j & 127;
            int kt = k >> 5, q = (k >> 3) & 3, e = k & 7;
            int t = n >> 4, m = n & 15;
            W2t[(((kt * 8 + t) * 64) + (q * 16 + m)) * 8 + e] = f2b(W2[k * DOUT + n]);
        }
    }
    {
        int* h = (int*)smem;
        if (tid < NBUCK) h[tid] = 0;
        __syncthreads();
        const int base = blk * EPB;             // partition = blk (256 partitions)
        #pragma unroll 1
        for (int it = 0; it < 4; ++it) {
            int e = base + it * 1024 + tid;
            if (e < base + EPB)
                atomicAdd(&h[ei[N_EDGES + e] >> 8], 1);
        }
        __syncthreads();
        if (tid < 256) blockHistT[blk * 256 + tid] = (tid < NBUCK) ? h[tid] : 0;
    }
    __threadfence();
    grid.sync();

    // ===== Phase B: gemm1 (blocks 0..97, 4 tile-subunits each) + scan (blocks 98..146) =====
    if (blk < 98) {
        const int sb = blk * 4 + (tid >> 8);    // tile id 0..391
        if (sb < G1TILES) {
            const int t256 = tid & 255;
            const int wave = t256 >> 6, lane = tid & 63;
            const int row0 = sb * 128 + wave * 32;
            const int m = lane & 15, q = lane >> 4;

            int r0 = row0 + m;
            int r1 = row0 + 16 + m;
            int rc0 = (r0 < N_NODES) ? r0 : 0;
            int rc1 = (r1 < N_NODES) ? r1 : 0;

            f32x4 acc0[8], acc1[8];
            #pragma unroll
            for (int t = 0; t < 8; ++t) {
                acc0[t] = (f32x4){0.f, 0.f, 0.f, 0.f};
                acc1[t] = (f32x4){0.f, 0.f, 0.f, 0.f};
            }

            const float* xr0 = x + (size_t)rc0 * DIN + q * 8;
            const float* xr1 = x + (size_t)rc1 * DIN + q * 8;
            const short* wb  = (const short*)W1t + lane * 8;

            #pragma unroll
            for (int kt = 0; kt < 8; ++kt) {
                float4 f0 = *(const float4*)(xr0 + kt * 32);
                float4 f1 = *(const float4*)(xr0 + kt * 32 + 4);
                float4 g0 = *(const float4*)(xr1 + kt * 32);
                float4 g1 = *(const float4*)(xr1 + kt * 32 + 4);
                bf16x8 a0, a1;
                a0[0] = (short)f2b(f0.x); a0[1] = (short)f2b(f0.y);
                a0[2] = (short)f2b(f0.z); a0[3] = (short)f2b(f0.w);
                a0[4] = (short)f2b(f1.x); a0[5] = (short)f2b(f1.y);
                a0[6] = (short)f2b(f1.z); a0[7] = (short)f2b(f1.w);
                a1[0] = (short)f2b(g0.x); a1[1] = (short)f2b(g0.y);
                a1[2] = (short)f2b(g0.z); a1[3] = (short)f2b(g0.w);
                a1[4] = (short)f2b(g1.x); a1[5] = (short)f2b(g1.y);
                a1[6] = (short)f2b(g1.z); a1[7] = (short)f2b(g1.w);
                #pragma unroll
                for (int t = 0; t < 8; ++t) {
                    bf16x8 b = *(const bf16x8*)(wb + (kt * 8 + t) * 512);
                    acc0[t] = __builtin_amdgcn_mfma_f32_16x16x32_bf16(a0, b, acc0[t], 0, 0, 0);
                    acc1[t] = __builtin_amdgcn_mfma_f32_16x16x32_bf16(a1, b, acc1[t], 0, 0, 0);
                }
            }

            #pragma unroll
            for (int reg = 0; reg < 4; ++reg) {
                int ra = row0 + q * 4 + reg;
                int rb = row0 + 16 + q * 4 + reg;
                if (ra < N_NODES) {
                    #pragma unroll
                    for (int t = 0; t < 8; ++t)
                        hb[(size_t)ra * DHID + t * 16 + m] = f2b(acc0[t][reg]);
                }
                if (rb < N_NODES) {
                    #pragma unroll
                    for (int t = 0; t < 8; ++t)
                        hb[(size_t)rb * DHID + t * 16 + m] = f2b(acc1[t][reg]);
                }
            }

            float es0[4] = {0,0,0,0}, ed0[4] = {0,0,0,0};
            float es1[4] = {0,0,0,0}, ed1[4] = {0,0,0,0};
            #pragma unroll
            for (int t = 0; t < 8; ++t) {
                float as = att_src[t * 16 + m];
                float ad = att_dst[t * 16 + m];
                #pragma unroll
                for (int reg = 0; reg < 4; ++reg) {
                    es0[reg] += acc0[t][reg] * as;
                    ed0[reg] += acc0[t][reg] * ad;
                    es1[reg] += acc1[t][reg] * as;
                    ed1[reg] += acc1[t][reg] * ad;
                }
            }
            #pragma unroll
            for (int off = 8; off; off >>= 1)
                #pragma unroll
                for (int reg = 0; reg < 4; ++reg) {
                    es0[reg] += __shfl_xor(es0[reg], off);
                    ed0[reg] += __shfl_xor(ed0[reg], off);
                    es1[reg] += __shfl_xor(es1[reg], off);
                    ed1[reg] += __shfl_xor(ed1[reg], off);
                }
            if (m == 0) {
                #pragma unroll
                for (int reg = 0; reg < 4; ++reg) {
                    int ra = row0 + q * 4 + reg;
                    int rb = row0 + 16 + q * 4 + reg;
                    if (ra < N_NODES) { es[ra] = es0[reg]; ed[ra] = ed0[reg]; }
                    if (rb < N_NODES) { es[rb] = es1[reg]; ed[rb] = ed1[reg]; }
                }
            }
        }
    } else if (blk < 147) {
        // scan: 49 blocks x 4 subunits = 196 buckets; whole block runs uniform barriers
        const int su = (blk - 98) * 4 + (tid >> 8);   // bucket 0..195
        const int t  = tid & 255;
        int* bs = (int*)smem + (tid >> 8) * 256;
        int* sc = (int*)smem + 1024 + (tid >> 8) * 256;

        int tot = 0;
        #pragma unroll 4
        for (int p = 0; p < 256; ++p) tot += blockHistT[p * 256 + t];
        bs[t] = tot;
        __syncthreads();
        #pragma unroll
        for (int off = 1; off < 256; off <<= 1) {
            int u = (t >= off) ? bs[t - off] : 0;
            __syncthreads();
            bs[t] += u;
            __syncthreads();
        }
        const int base = (su == 0) ? 0 : bs[su - 1];

        int c = blockHistT[t * 256 + su];
        sc[t] = c;
        __syncthreads();
        #pragma unroll
        for (int off = 1; off < 256; off <<= 1) {
            int u = (t >= off) ? sc[t - off] : 0;
            __syncthreads();
            sc[t] += u;
            __syncthreads();
        }
        matrixScan[su * 256 + t] = base + sc[t] - c;   // exclusive prefix
    }
    __threadfence();
    grid.sync();

    // ===== Phase C: binpass (all 256 blocks, partition = blk) =====
    {
        int* lcur = (int*)smem;
        if (tid < NBUCK) lcur[tid] = matrixScan[tid * 256 + blk];
        __syncthreads();
        const int base = blk * EPB;
        #pragma unroll 1
        for (int it = 0; it < 4; ++it) {
            int e = base + it * 1024 + tid;
            if (e < base + EPB) {
                int s = ei[e];
                int d = ei[N_EDGES + e];
                float a  = es[s] + ed[d];
                float sg = 1.f / (1.f + __expf(-a));
                float w  = __expf(sg);
                int pos = atomicAdd(&lcur[d >> 8], 1);
                binned[pos] = make_int2(s | ((d & 255) << 16), __float_as_int(w));
            }
        }
    }
    __threadfence();
    grid.sync();

    // ===== Phase D: sortpass (blocks 0..195 = buckets) =====
    if (blk < NBUCK) {
        int* lhist = (int*)smem;
        int* lscan = lhist + 256;
        int* lcur  = lhist + 512;
        const int b = blk;
        const int start = matrixScan[b * 256];
        const int end   = (b == NBUCK - 1) ? N_EDGES : matrixScan[(b + 1) * 256];
        const int cnt   = end - start;

        if (tid < 256) lhist[tid] = 0;
        __syncthreads();
        for (int i = tid; i < cnt; i += 1024)
            atomicAdd(&lhist[(binned[start + i].x >> 16) & 255], 1);
        __syncthreads();

        int v = 0;
        if (tid < 256) { v = lhist[tid]; lscan[tid] = v; }
        __syncthreads();
        #pragma unroll
        for (int off = 1; off < 256; off <<= 1) {
            int u = 0;
            if (tid < 256 && tid >= off) u = lscan[tid - off];
            __syncthreads();
            if (tid < 256) lscan[tid] += u;
            __syncthreads();
        }
        if (tid < 256) {
            int excl = lscan[tid] - v;
            int node = (b << 8) + tid;
            if (node < N_NODES) { offset[node] = start + excl; count[node] = v; }
            lcur[tid] = excl;
        }
        __syncthreads();

        for (int i = tid; i < cnt; i += 1024) {
            int2 ent = binned[start + i];
            int dlow = (ent.x >> 16) & 255;
            int pos = atomicAdd(&lcur[dlow], 1);
            sortedSW[start + pos] = make_int2(ent.x & 0xFFFF, ent.y);
        }
    }
    __threadfence();
    grid.sync();

    // ===== Phase E: agg + gemm2 (4 subunits/block x 4 iterations; R6 full-wave gather) =====
    {
        unsigned short (*ht)[HTP] =
            (unsigned short(*)[HTP])(smem + (tid >> 8) * 16 * HTP * 2);  // 4x4352B
        const int t256 = tid & 255;
        const int wv = t256 >> 6, lane = tid & 63;
        const int sgid = blk * 4 + (tid >> 8);      // subunit 0..1023

        #pragma unroll 1
        for (int itg = 0; itg < 4; ++itg) {
            const int g = sgid + itg * 1024;        // node-group id
            const bool act = (g < 3125);            // 3125*16 = 50000
            const int nbase = g * 16;

            if (act) {
                #pragma unroll 1
                for (int s = 0; s < 4; ++s) {
                    const int row = wv * 4 + s;
                    const int node = nbase + row;

                    int beg = offset[node];
                    int deg = count[node];

                    float2 acc = make_float2(0.f, 0.f);
                    float wsum = 0.f;

                    for (int bb = 0; bb < deg; bb += 64) {
                        int cnt = min(64, deg - bb);
                        int2 sw = (lane < cnt) ? sortedSW[beg + bb + lane] : make_int2(0, 0);
                        int j = 0;

#define TIER(T)                                                                 \
                        for (; j + T <= cnt; j += T) {                          \
                            unsigned uu[T]; float ww[T];                        \
                            _Pragma("unroll")                                   \
                            for (int k = 0; k < T; ++k) {                       \
                                int s_ = __builtin_amdgcn_readlane(sw.x, j + k);\
                                uu[k] = *(const unsigned*)(hb + (size_t)s_ * DHID + 2 * lane); \
                            }                                                   \
                            _Pragma("unroll")                                   \
                            for (int k = 0; k < T; ++k)                         \
                                ww[k] = __uint_as_float(                        \
                                    (unsigned)__builtin_amdgcn_readlane(sw.y, j + k)); \
                            _Pragma("unroll")                                   \
                            for (int k = 0; k < T; ++k) {                       \
                                wsum  += ww[k];                                 \
                                acc.x += ww[k] * __uint_as_float(uu[k] << 16);  \
                                acc.y += ww[k] * __uint_as_float(uu[k] & 0xffff0000u); \
                            }                                                   \
                        }

                        TIER(16)
                        TIER(8)
                        TIER(4)
#undef TIER
                        for (; j < cnt; ++j) {
                            int   sj = __builtin_amdgcn_readlane(sw.x, j);
                            float wj = __uint_as_float((unsigned)__builtin_amdgcn_readlane(sw.y, j));
                            unsigned u = *(const unsigned*)(hb + (size_t)sj * DHID + 2 * lane);
                            acc.x += wj * __uint_as_float(u << 16);
                            acc.y += wj * __uint_as_float(u & 0xffff0000u);
                            wsum  += wj;
                        }
                    }
                    float inv = (deg > 0) ? 1.f / wsum : 0.f;
                    float v0 = acc.x * inv, v1 = acc.y * inv;
                    float e0 = v0 > 0.f ? v0 : (__expf(v0) - 1.f);
                    float e1 = v1 > 0.f ? v1 : (__expf(v1) - 1.f);
                    *(unsigned*)&ht[row][2 * lane] =
                        (unsigned)f2b(e0) | ((unsigned)f2b(e1) << 16);
                }
            }
            __syncthreads();

            if (act) {
                const int m = lane & 15, q = lane >> 4;
                f32x4 c0 = (f32x4){0.f, 0.f, 0.f, 0.f};
                f32x4 c1 = (f32x4){0.f, 0.f, 0.f, 0.f};
                const short* wb = (const short*)W2t + lane * 8;
                const int t0 = wv * 2, t1 = wv * 2 + 1;

                #pragma unroll
                for (int kt = 0; kt < 4; ++kt) {
                    bf16x8 a = *(const bf16x8*)&ht[m][q * 8 + kt * 32];
                    bf16x8 b0 = *(const bf16x8*)(wb + (kt * 8 + t0) * 512);
                    bf16x8 b1 = *(const bf16x8*)(wb + (kt * 8 + t1) * 512);
                    c0 = __builtin_amdgcn_mfma_f32_16x16x32_bf16(a, b0, c0, 0, 0, 0);
                    c1 = __builtin_amdgcn_mfma_f32_16x16x32_bf16(a, b1, c1, 0, 0, 0);
                }

                #pragma unroll
                for (int reg = 0; reg < 4; ++reg) {
                    int node = nbase + q * 4 + reg;
                    out[(size_t)node * DOUT + t0 * 16 + m] = c0[reg];
                    out[(size_t)node * DOUT + t1 * 16 + m] = c1[reg];
                }
            }
            __syncthreads();
        }
    }
}

extern "C" void kernel_launch(void* const* d_in, const int* in_sizes, int n_in,
                              void* d_out, int out_size, void* d_ws, size_t ws_size,
                              hipStream_t stream)
{
    const float* x    = (const float*)d_in[0];
    const int*   ei   = (const int*)d_in[1];
    const float* W1   = (const float*)d_in[2];
    const float* asrc = (const float*)d_in[3];
    const float* adst = (const float*)d_in[4];
    const float* W2   = (const float*)d_in[5];
    float*       out  = (float*)d_out;

    // ---- workspace layout (~27 MB) ----
    char* p = (char*)d_ws;
    unsigned short* hb  = (unsigned short*)p;  p += (size_t)N_NODES * DHID * 2;  // 12.8 MB
    unsigned short* W1t = (unsigned short*)p;  p += (size_t)DHID * DIN * 2;      // 64 KB
    unsigned short* W2t = (unsigned short*)p;  p += (size_t)DOUT * DHID * 2;     // 32 KB
    float* es     = (float*)p;  p += (size_t)N_NODES * 4;
    float* ed     = (float*)p;  p += (size_t)N_NODES * 4;
    int*   offset = (int*)p;    p += (size_t)N_NODES * 4;
    int*   count  = (int*)p;    p += (size_t)N_NODES * 4;
    int*   blockHistT   = (int*)p; p += (size_t)256 * 256 * 4;                   // 256 KB
    int*   matrixScan   = (int*)p; p += (size_t)NBUCK * 256 * 4;                 // 200 KB
    int2*  binned   = (int2*)p; p += (size_t)N_EDGES * 8;                        // 6.4 MB
    int2*  sortedSW = (int2*)p; p += (size_t)N_EDGES * 8;                        // 6.4 MB

    void* kargs[] = {
        (void*)&x, (void*)&ei, (void*)&W1, (void*)&asrc, (void*)&adst, (void*)&W2,
        (void*)&W1t, (void*)&W2t, (void*)&blockHistT, (void*)&matrixScan,
        (void*)&hb, (void*)&es, (void*)&ed, (void*)&binned, (void*)&sortedSW,
        (void*)&offset, (void*)&count, (void*)&out
    };
    hipLaunchCooperativeKernel((const void*)mega_kernel, dim3(256), dim3(1024),
                               kargs, 0, stream);
}

// Round 9
// 719.337 us; speedup vs baseline: 1.0917x; 1.0917x over previous
//
#include <hip/hip_runtime.h>
#include <hip/hip_bf16.h>
#include <hip/hip_cooperative_groups.h>

namespace cg = cooperative_groups;

#define N_NODES 50000
#define N_EDGES 800000
#define DIN 256
#define DHID 128
#define DOUT 128
#define NBUCK 196     // buckets = dst >> 8
#define EPB 3125      // edges per partition (256*3125 = 800000 exact)
#define HTP 136       // LDS ht row pitch in shorts (272B, 16B-aligned)

typedef __attribute__((ext_vector_type(8))) short bf16x8;
typedef __attribute__((ext_vector_type(4))) float f32x4;

__device__ inline unsigned short f2b(float f) {
    __hip_bfloat16 b = __float2bfloat16(f);
    return *reinterpret_cast<unsigned short*>(&b);
}

// ================= single cooperative mega-kernel, v2 =================
// 256 blocks x 1024 threads, 1 block/CU. NO min-waves launch bound (R8's
// (1024,4) clamped VGPR to 64 -> gemm1 acc spilled to scratch -> 4x slowdown).
// gemm1 shrunk to M=16/wave (acc = 32 VGPR) so the whole kernel fits the
// 128-VGPR/16-wave budget without spill.
__global__ __launch_bounds__(1024) void mega_kernel(
    const float* __restrict__ x,
    const int* __restrict__ ei,
    const float* __restrict__ W1,
    const float* __restrict__ att_src,
    const float* __restrict__ att_dst,
    const float* __restrict__ W2,
    unsigned short* __restrict__ W1t,
    unsigned short* __restrict__ W2t,
    int* __restrict__ blockHistT,
    int* __restrict__ matrixScan,
    unsigned short* __restrict__ hb,
    float* __restrict__ es,
    float* __restrict__ ed,
    int2* __restrict__ binned,
    int2* __restrict__ sortedSW,
    int* __restrict__ offset,
    int* __restrict__ count,
    float* __restrict__ out)
{
    cg::grid_group grid = cg::this_grid();
    __shared__ __align__(16) char smem[18432];
    const int blk = blockIdx.x;
    const int tid = threadIdx.x;

    // ===== Phase A: weight transpose+cast (fragment-ordered) + edge bucket hist =====
    if (blk < 48) {                             // 48*1024 = 49152 = 32768 + 16384
        int i = blk * 1024 + tid;
        if (i < DIN * DHID) {                   // W1: n=out channel, k=in channel
            int n = i >> 8, k = i & 255;
            int kt = k >> 5, q = (k >> 3) & 3, e = k & 7;
            int t = n >> 4, m = n & 15;
            W1t[(((kt * 8 + t) * 64) + (q * 16 + m)) * 8 + e] = f2b(W1[k * DHID + n]);
        } else {
            int j = i - DIN * DHID;
            int n = j >> 7, k = j & 127;
            int kt = k >> 5, q = (k >> 3) & 3, e = k & 7;
            int t = n >> 4, m = n & 15;
            W2t[(((kt * 8 + t) * 64) + (q * 16 + m)) * 8 + e] = f2b(W2[k * DOUT + n]);
        }
    }
    {
        int* h = (int*)smem;
        if (tid < NBUCK) h[tid] = 0;
        __syncthreads();
        const int base = blk * EPB;             // partition = blk
        #pragma unroll 1
        for (int it = 0; it < 4; ++it) {
            int e = base + it * 1024 + tid;
            if (e < base + EPB)
                atomicAdd(&h[ei[N_EDGES + e] >> 8], 1);
        }
        __syncthreads();
        if (tid < 256) blockHistT[blk * 256 + tid] = (tid < NBUCK) ? h[tid] : 0;
    }
    __threadfence();
    grid.sync();

    // ===== Phase B: gemm1 (barrier-free, M=16/wave, all 256 blocks) then scan =====
    {
        const int w = tid >> 6, lane = tid & 63;
        const int chunk = blk + (w << 8);       // 16 waves: chunks blk, blk+256, ...
        if (chunk < 3125) {                     // 3125*16 = 50000 exact -> no bounds checks
            const int row0 = chunk * 16;
            const int m = lane & 15, q = lane >> 4;
            const int r = row0 + m;

            f32x4 acc[8];
            #pragma unroll
            for (int t = 0; t < 8; ++t) acc[t] = (f32x4){0.f, 0.f, 0.f, 0.f};

            const float* xr = x + (size_t)r * DIN + q * 8;
            const short* wb = (const short*)W1t + lane * 8;

            #pragma unroll
            for (int kt = 0; kt < 8; ++kt) {
                float4 f0 = *(const float4*)(xr + kt * 32);
                float4 f1 = *(const float4*)(xr + kt * 32 + 4);
                bf16x8 a;
                a[0] = (short)f2b(f0.x); a[1] = (short)f2b(f0.y);
                a[2] = (short)f2b(f0.z); a[3] = (short)f2b(f0.w);
                a[4] = (short)f2b(f1.x); a[5] = (short)f2b(f1.y);
                a[6] = (short)f2b(f1.z); a[7] = (short)f2b(f1.w);
                #pragma unroll
                for (int t = 0; t < 8; ++t) {
                    bf16x8 b = *(const bf16x8*)(wb + (kt * 8 + t) * 512);
                    acc[t] = __builtin_amdgcn_mfma_f32_16x16x32_bf16(a, b, acc[t], 0, 0, 0);
                }
            }

            #pragma unroll
            for (int reg = 0; reg < 4; ++reg) {
                int rr = row0 + q * 4 + reg;
                #pragma unroll
                for (int t = 0; t < 8; ++t)
                    hb[(size_t)rr * DHID + t * 16 + m] = f2b(acc[t][reg]);
            }

            float esr[4] = {0,0,0,0}, edr[4] = {0,0,0,0};
            #pragma unroll
            for (int t = 0; t < 8; ++t) {
                float as = att_src[t * 16 + m];
                float ad = att_dst[t * 16 + m];
                #pragma unroll
                for (int reg = 0; reg < 4; ++reg) {
                    esr[reg] += acc[t][reg] * as;
                    edr[reg] += acc[t][reg] * ad;
                }
            }
            #pragma unroll
            for (int off = 8; off; off >>= 1)
                #pragma unroll
                for (int reg = 0; reg < 4; ++reg) {
                    esr[reg] += __shfl_xor(esr[reg], off);
                    edr[reg] += __shfl_xor(edr[reg], off);
                }
            if (m == 0) {
                #pragma unroll
                for (int reg = 0; reg < 4; ++reg) {
                    int rr = row0 + q * 4 + reg;
                    es[rr] = esr[reg]; ed[rr] = edr[reg];
                }
            }
        }
    }
    __syncthreads();
    // scan (depends only on Phase A's hist): blocks 0..195 = buckets
    if (blk < NBUCK) {
        int* bs = (int*)smem;
        int* sc = bs + 256;
        const int t = tid;
        const int b = blk;

        if (t < 256) {
            int tot = 0;
            #pragma unroll 4
            for (int p = 0; p < 256; ++p) tot += blockHistT[p * 256 + t];
            bs[t] = tot;
        }
        __syncthreads();
        #pragma unroll
        for (int off = 1; off < 256; off <<= 1) {
            int u = 0;
            if (t < 256 && t >= off) u = bs[t - off];
            __syncthreads();
            if (t < 256) bs[t] += u;
            __syncthreads();
        }
        const int base = (b == 0) ? 0 : bs[b - 1];

        int c = 0;
        if (t < 256) { c = blockHistT[t * 256 + b]; sc[t] = c; }
        __syncthreads();
        #pragma unroll
        for (int off = 1; off < 256; off <<= 1) {
            int u = 0;
            if (t < 256 && t >= off) u = sc[t - off];
            __syncthreads();
            if (t < 256) sc[t] += u;
            __syncthreads();
        }
        if (t < 256) matrixScan[b * 256 + t] = base + sc[t] - c;   // exclusive prefix
    }
    __threadfence();
    grid.sync();

    // ===== Phase C: binpass (all 256 blocks, partition = blk) =====
    {
        int* lcur = (int*)smem;
        if (tid < NBUCK) lcur[tid] = matrixScan[tid * 256 + blk];
        __syncthreads();
        const int base = blk * EPB;
        #pragma unroll 1
        for (int it = 0; it < 4; ++it) {
            int e = base + it * 1024 + tid;
            if (e < base + EPB) {
                int s = ei[e];
                int d = ei[N_EDGES + e];
                float a  = es[s] + ed[d];
                float sg = 1.f / (1.f + __expf(-a));
                float w  = __expf(sg);
                int pos = atomicAdd(&lcur[d >> 8], 1);
                binned[pos] = make_int2(s | ((d & 255) << 16), __float_as_int(w));
            }
        }
    }
    __threadfence();
    grid.sync();

    // ===== Phase D: sortpass (blocks 0..195 = buckets) =====
    if (blk < NBUCK) {
        int* lhist = (int*)smem;
        int* lscan = lhist + 256;
        int* lcur  = lhist + 512;
        const int b = blk;
        const int start = matrixScan[b * 256];
        const int end   = (b == NBUCK - 1) ? N_EDGES : matrixScan[(b + 1) * 256];
        const int cnt   = end - start;

        if (tid < 256) lhist[tid] = 0;
        __syncthreads();
        for (int i = tid; i < cnt; i += 1024)
            atomicAdd(&lhist[(binned[start + i].x >> 16) & 255], 1);
        __syncthreads();

        int v = 0;
        if (tid < 256) { v = lhist[tid]; lscan[tid] = v; }
        __syncthreads();
        #pragma unroll
        for (int off = 1; off < 256; off <<= 1) {
            int u = 0;
            if (tid < 256 && tid >= off) u = lscan[tid - off];
            __syncthreads();
            if (tid < 256) lscan[tid] += u;
            __syncthreads();
        }
        if (tid < 256) {
            int excl = lscan[tid] - v;
            int node = (b << 8) + tid;
            if (node < N_NODES) { offset[node] = start + excl; count[node] = v; }
            lcur[tid] = excl;
        }
        __syncthreads();

        for (int i = tid; i < cnt; i += 1024) {
            int2 ent = binned[start + i];
            int dlow = (ent.x >> 16) & 255;
            int pos = atomicAdd(&lcur[dlow], 1);
            sortedSW[start + pos] = make_int2(ent.x & 0xFFFF, ent.y);
        }
    }
    __threadfence();
    grid.sync();

    // ===== Phase E: agg + gemm2 (4 subunits/block x 4 iterations; R6 gather) =====
    {
        unsigned short (*ht)[HTP] =
            (unsigned short(*)[HTP])(smem + (tid >> 8) * 16 * HTP * 2);  // 4x4352B
        const int t256 = tid & 255;
        const int wv = t256 >> 6, lane = tid & 63;
        const int sgid = blk * 4 + (tid >> 8);      // subunit 0..1023

        #pragma unroll 1
        for (int itg = 0; itg < 4; ++itg) {
            const int g = sgid + itg * 1024;        // node-group id
            const bool act = (g < 3125);            // 3125*16 = 50000
            const int nbase = g * 16;

            if (act) {
                #pragma unroll 1
                for (int s = 0; s < 4; ++s) {
                    const int row = wv * 4 + s;
                    const int node = nbase + row;

                    int beg = offset[node];
                    int deg = count[node];

                    float2 acc = make_float2(0.f, 0.f);
                    float wsum = 0.f;

                    for (int bb = 0; bb < deg; bb += 64) {
                        int cnt = min(64, deg - bb);
                        int2 sw = (lane < cnt) ? sortedSW[beg + bb + lane] : make_int2(0, 0);
                        int j = 0;

#define TIER(T)                                                                 \
                        for (; j + T <= cnt; j += T) {                          \
                            unsigned uu[T]; float ww[T];                        \
                            _Pragma("unroll")                                   \
                            for (int k = 0; k < T; ++k) {                       \
                                int s_ = __builtin_amdgcn_readlane(sw.x, j + k);\
                                uu[k] = *(const unsigned*)(hb + (size_t)s_ * DHID + 2 * lane); \
                            }                                                   \
                            _Pragma("unroll")                                   \
                            for (int k = 0; k < T; ++k)                         \
                                ww[k] = __uint_as_float(                        \
                                    (unsigned)__builtin_amdgcn_readlane(sw.y, j + k)); \
                            _Pragma("unroll")                                   \
                            for (int k = 0; k < T; ++k) {                       \
                                wsum  += ww[k];                                 \
                                acc.x += ww[k] * __uint_as_float(uu[k] << 16);  \
                                acc.y += ww[k] * __uint_as_float(uu[k] & 0xffff0000u); \
                            }                                                   \
                        }

                        TIER(16)
                        TIER(8)
                        TIER(4)
#undef TIER
                        for (; j < cnt; ++j) {
                            int   sj = __builtin_amdgcn_readlane(sw.x, j);
                            float wj = __uint_as_float((unsigned)__builtin_amdgcn_readlane(sw.y, j));
                            unsigned u = *(const unsigned*)(hb + (size_t)sj * DHID + 2 * lane);
                            acc.x += wj * __uint_as_float(u << 16);
                            acc.y += wj * __uint_as_float(u & 0xffff0000u);
                            wsum  += wj;
                        }
                    }
                    float inv = (deg > 0) ? 1.f / wsum : 0.f;
                    float v0 = acc.x * inv, v1 = acc.y * inv;
                    float e0 = v0 > 0.f ? v0 : (__expf(v0) - 1.f);
                    float e1 = v1 > 0.f ? v1 : (__expf(v1) - 1.f);
                    *(unsigned*)&ht[row][2 * lane] =
                        (unsigned)f2b(e0) | ((unsigned)f2b(e1) << 16);
                }
            }
            __syncthreads();

            if (act) {
                const int m = lane & 15, q = lane >> 4;
                f32x4 c0 = (f32x4){0.f, 0.f, 0.f, 0.f};
                f32x4 c1 = (f32x4){0.f, 0.f, 0.f, 0.f};
                const short* wb = (const short*)W2t + lane * 8;
                const int t0 = wv * 2, t1 = wv * 2 + 1;

                #pragma unroll
                for (int kt = 0; kt < 4; ++kt) {
                    bf16x8 a = *(const bf16x8*)&ht[m][q * 8 + kt * 32];
                    bf16x8 b0 = *(const bf16x8*)(wb + (kt * 8 + t0) * 512);
                    bf16x8 b1 = *(const bf16x8*)(wb + (kt * 8 + t1) * 512);
                    c0 = __builtin_amdgcn_mfma_f32_16x16x32_bf16(a, b0, c0, 0, 0, 0);
                    c1 = __builtin_amdgcn_mfma_f32_16x16x32_bf16(a, b1, c1, 0, 0, 0);
                }

                #pragma unroll
                for (int reg = 0; reg < 4; ++reg) {
                    int node = nbase + q * 4 + reg;
                    out[(size_t)node * DOUT + t0 * 16 + m] = c0[reg];
                    out[(size_t)node * DOUT + t1 * 16 + m] = c1[reg];
                }
            }
            __syncthreads();
        }
    }
}

extern "C" void kernel_launch(void* const* d_in, const int* in_sizes, int n_in,
                              void* d_out, int out_size, void* d_ws, size_t ws_size,
                              hipStream_t stream)
{
    const float* x    = (const float*)d_in[0];
    const int*   ei   = (const int*)d_in[1];
    const float* W1   = (const float*)d_in[2];
    const float* asrc = (const float*)d_in[3];
    const float* adst = (const float*)d_in[4];
    const float* W2   = (const float*)d_in[5];
    float*       out  = (float*)d_out;

    // ---- workspace layout (~27 MB) ----
    char* p = (char*)d_ws;
    unsigned short* hb  = (unsigned short*)p;  p += (size_t)N_NODES * DHID * 2;  // 12.8 MB
    unsigned short* W1t = (unsigned short*)p;  p += (size_t)DHID * DIN * 2;      // 64 KB
    unsigned short* W2t = (unsigned short*)p;  p += (size_t)DOUT * DHID * 2;     // 32 KB
    float* es     = (float*)p;  p += (size_t)N_NODES * 4;
    float* ed     = (float*)p;  p += (size_t)N_NODES * 4;
    int*   offset = (int*)p;    p += (size_t)N_NODES * 4;
    int*   count  = (int*)p;    p += (size_t)N_NODES * 4;
    int*   blockHistT   = (int*)p; p += (size_t)256 * 256 * 4;                   // 256 KB
    int*   matrixScan   = (int*)p; p += (size_t)NBUCK * 256 * 4;                 // 200 KB
    int2*  binned   = (int2*)p; p += (size_t)N_EDGES * 8;                        // 6.4 MB
    int2*  sortedSW = (int2*)p; p += (size_t)N_EDGES * 8;                        // 6.4 MB

    void* kargs[] = {
        (void*)&x, (void*)&ei, (void*)&W1, (void*)&asrc, (void*)&adst, (void*)&W2,
        (void*)&W1t, (void*)&W2t, (void*)&blockHistT, (void*)&matrixScan,
        (void*)&hb, (void*)&es, (void*)&ed, (void*)&binned, (void*)&sortedSW,
        (void*)&offset, (void*)&count, (void*)&out
    };
    hipLaunchCooperativeKernel((const void*)mega_kernel, dim3(256), dim3(1024),
                               kargs, 0, stream);
}

// Round 10
// 185.915 us; speedup vs baseline: 4.2241x; 3.8692x over previous
//
#include <hip/hip_runtime.h>
#include <hip/hip_bf16.h>

#define N_NODES 50000
#define N_EDGES 800000
#define DIN 256
#define DHID 128
#define DOUT 128
#define NBUCK 196     // buckets = dst >> 8
#define BINBLK 256    // histogram partitions (matrixScan row width)
#define EPB 3125      // edges per partition (256*3125 = 800000 exact)
#define G1TILES 391   // ceil(50000/128) gemm1 tiles (4 waves x 32 rows)
#define HTP 136       // LDS ht row pitch in shorts (272B, 16B-aligned)
#define EBCAP 8192    // LDS edge buffer capacity per bucket (mean 4096, +24 sigma)

typedef __attribute__((ext_vector_type(8))) short bf16x8;
typedef __attribute__((ext_vector_type(4))) float f32x4;

__device__ inline unsigned short f2b(float f) {
    __hip_bfloat16 b = __float2bfloat16(f);
    return *reinterpret_cast<unsigned short*>(&b);
}

// ---------------- D1: weight transpose+cast (fragment-ordered) + edge bucket hist.
// W1t/W2t layout: 16B chunk ((kt*8 + t)*64 + (q*16 + m)) holds bf16 W[k = kt*32+q*8+e][n = t*16+m]
// -> a wave reads 64 consecutive 16B chunks per (kt,t): one fully-coalesced 1KB L2 access.
// blockHistT layout: [partition][bucket] (padded to 256) so scan-side reads coalesce.
__global__ __launch_bounds__(1024) void convW_lhist_kernel(
    const float* __restrict__ W1, const float* __restrict__ W2,
    const int* __restrict__ ei,
    unsigned short* __restrict__ W1t, unsigned short* __restrict__ W2t,
    int* __restrict__ blockHistT)
{
    __shared__ int h[NBUCK];
    const int blk = blockIdx.x;
    const int tid = threadIdx.x;

    if (blk < 48) {                             // 48*1024 = 49152 = 32768 + 16384
        int i = blk * 1024 + tid;
        if (i < DIN * DHID) {                   // W1: n=out channel, k=in channel
            int n = i >> 8, k = i & 255;
            int kt = k >> 5, q = (k >> 3) & 3, e = k & 7;
            int t = n >> 4, m = n & 15;
            W1t[(((kt * 8 + t) * 64) + (q * 16 + m)) * 8 + e] = f2b(W1[k * DHID + n]);
        } else {
            int j = i - DIN * DHID;
            int n = j >> 7, k = j & 127;
            int kt = k >> 5, q = (k >> 3) & 3, e = k & 7;
            int t = n >> 4, m = n & 15;
            W2t[(((kt * 8 + t) * 64) + (q * 16 + m)) * 8 + e] = f2b(W2[k * DOUT + n]);
        }
        return;
    }

    // ---- lhist part: per-partition bucket histogram (bucket = dst >> 8)
    const int b = blk - 48;                     // partition [0, 256)
    if (tid < NBUCK) h[tid] = 0;
    __syncthreads();
    const int base = b * EPB;
    #pragma unroll 1
    for (int it = 0; it < 4; ++it) {
        int e = base + it * 1024 + tid;
        if (e < base + EPB)
            atomicAdd(&h[ei[N_EDGES + e] >> 8], 1);
    }
    __syncthreads();
    if (tid < 256) blockHistT[b * 256 + tid] = (tid < NBUCK) ? h[tid] : 0;  // coalesced
}

// ---------------- D2: gemm1 (+ fused scan blocks): hb = bf16( bf16(x) @ W1 ).
// MFMA 16x16x32, M=32/wave, B direct from L2 (fragment-ordered, no LDS, no barrier).
// Blocks [G1TILES, G1TILES+NBUCK): prefix scan -> matrixScan (coalesced totals).
__global__ __launch_bounds__(256) void gemm1_scan_kernel(
    const float* __restrict__ x,
    const unsigned short* __restrict__ W1t,
    const float* __restrict__ att_src,
    const float* __restrict__ att_dst,
    const int* __restrict__ blockHistT,
    unsigned short* __restrict__ hb,
    float* __restrict__ es,
    float* __restrict__ ed,
    int* __restrict__ matrixScan)
{
    __shared__ int bs[256];
    __shared__ int sc[256];
    const int tid = threadIdx.x;

    if (blockIdx.x >= G1TILES) {
        // ---- scan part ----
        const int b = blockIdx.x - G1TILES;   // bucket [0,196)

        int tot = 0;
        #pragma unroll 4
        for (int p = 0; p < 256; ++p) tot += blockHistT[p * 256 + tid];
        bs[tid] = tot;
        __syncthreads();
        #pragma unroll
        for (int off = 1; off < 256; off <<= 1) {
            int u = (tid >= off) ? bs[tid - off] : 0;
            __syncthreads();
            bs[tid] += u;
            __syncthreads();
        }
        const int base = (b == 0) ? 0 : bs[b - 1];

        int c = blockHistT[tid * 256 + b];    // partition tid's count for bucket b
        sc[tid] = c;
        __syncthreads();
        #pragma unroll
        for (int off = 1; off < 256; off <<= 1) {
            int u = (tid >= off) ? sc[tid - off] : 0;
            __syncthreads();
            sc[tid] += u;
            __syncthreads();
        }
        matrixScan[b * 256 + tid] = base + sc[tid] - c;   // exclusive prefix
        return;
    }

    // ---- gemm1 part: 4 waves x 32 rows = 128 rows per block ----
    const int wave = tid >> 6, lane = tid & 63;
    const int row0 = blockIdx.x * 128 + wave * 32;
    const int m = lane & 15, q = lane >> 4;

    int r0 = row0 + m;
    int r1 = row0 + 16 + m;
    int rc0 = (r0 < N_NODES) ? r0 : 0;
    int rc1 = (r1 < N_NODES) ? r1 : 0;

    f32x4 acc0[8], acc1[8];
    #pragma unroll
    for (int t = 0; t < 8; ++t) {
        acc0[t] = (f32x4){0.f, 0.f, 0.f, 0.f};
        acc1[t] = (f32x4){0.f, 0.f, 0.f, 0.f};
    }

    const float* xr0 = x + (size_t)rc0 * DIN + q * 8;
    const float* xr1 = x + (size_t)rc1 * DIN + q * 8;
    const short* wb  = (const short*)W1t + lane * 8;   // + (kt*8+t)*512 shorts

    #pragma unroll
    for (int kt = 0; kt < 8; ++kt) {
        float4 f0 = *(const float4*)(xr0 + kt * 32);
        float4 f1 = *(const float4*)(xr0 + kt * 32 + 4);
        float4 g0 = *(const float4*)(xr1 + kt * 32);
        float4 g1 = *(const float4*)(xr1 + kt * 32 + 4);
        bf16x8 a0, a1;
        a0[0] = (short)f2b(f0.x); a0[1] = (short)f2b(f0.y);
        a0[2] = (short)f2b(f0.z); a0[3] = (short)f2b(f0.w);
        a0[4] = (short)f2b(f1.x); a0[5] = (short)f2b(f1.y);
        a0[6] = (short)f2b(f1.z); a0[7] = (short)f2b(f1.w);
        a1[0] = (short)f2b(g0.x); a1[1] = (short)f2b(g0.y);
        a1[2] = (short)f2b(g0.z); a1[3] = (short)f2b(g0.w);
        a1[4] = (short)f2b(g1.x); a1[5] = (short)f2b(g1.y);
        a1[6] = (short)f2b(g1.z); a1[7] = (short)f2b(g1.w);
        #pragma unroll
        for (int t = 0; t < 8; ++t) {
            bf16x8 b = *(const bf16x8*)(wb + (kt * 8 + t) * 512);
            acc0[t] = __builtin_amdgcn_mfma_f32_16x16x32_bf16(a0, b, acc0[t], 0, 0, 0);
            acc1[t] = __builtin_amdgcn_mfma_f32_16x16x32_bf16(a1, b, acc1[t], 0, 0, 0);
        }
    }

    #pragma unroll
    for (int reg = 0; reg < 4; ++reg) {
        int ra = row0 + q * 4 + reg;
        int rb = row0 + 16 + q * 4 + reg;
        if (ra < N_NODES) {
            #pragma unroll
            for (int t = 0; t < 8; ++t)
                hb[(size_t)ra * DHID + t * 16 + m] = f2b(acc0[t][reg]);
        }
        if (rb < N_NODES) {
            #pragma unroll
            for (int t = 0; t < 8; ++t)
                hb[(size_t)rb * DHID + t * 16 + m] = f2b(acc1[t][reg]);
        }
    }

    float es0[4] = {0,0,0,0}, ed0[4] = {0,0,0,0};
    float es1[4] = {0,0,0,0}, ed1[4] = {0,0,0,0};
    #pragma unroll
    for (int t = 0; t < 8; ++t) {
        float as = att_src[t * 16 + m];
        float ad = att_dst[t * 16 + m];
        #pragma unroll
        for (int reg = 0; reg < 4; ++reg) {
            es0[reg] += acc0[t][reg] * as;
            ed0[reg] += acc0[t][reg] * ad;
            es1[reg] += acc1[t][reg] * as;
            ed1[reg] += acc1[t][reg] * ad;
        }
    }
    #pragma unroll
    for (int off = 8; off; off >>= 1)
        #pragma unroll
        for (int reg = 0; reg < 4; ++reg) {
            es0[reg] += __shfl_xor(es0[reg], off);
            ed0[reg] += __shfl_xor(ed0[reg], off);
            es1[reg] += __shfl_xor(es1[reg], off);
            ed1[reg] += __shfl_xor(ed1[reg], off);
        }
    if (m == 0) {
        #pragma unroll
        for (int reg = 0; reg < 4; ++reg) {
            int ra = row0 + q * 4 + reg;
            int rb = row0 + 16 + q * 4 + reg;
            if (ra < N_NODES) { es[ra] = es0[reg]; ed[ra] = ed0[reg]; }
            if (rb < N_NODES) { es[rb] = es1[reg]; ed[rb] = ed1[reg]; }
        }
    }
}

// ---------------- D3: binpass — two-level multi-split, per-(partition,bucket) PRIVATE
// ranges (single-writer 64B-line ownership: critical on multi-XCD, proven R5).
__global__ __launch_bounds__(1024) void binpass_kernel(
    const int* __restrict__ ei,
    const float* __restrict__ es,
    const float* __restrict__ ed,
    const int* __restrict__ matrixScan,
    int2* __restrict__ binned)
{
    __shared__ int lcur[NBUCK];
    const int t = threadIdx.x, blk = blockIdx.x;
    if (t < NBUCK) lcur[t] = matrixScan[t * 256 + blk];
    __syncthreads();
    const int base = blk * EPB;
    #pragma unroll 1
    for (int it = 0; it < 4; ++it) {
        int e = base + it * 1024 + t;
        if (e < base + EPB) {
            int s = ei[e];
            int d = ei[N_EDGES + e];
            float a  = es[s] + ed[d];
            float sg = 1.f / (1.f + __expf(-a));
            float w  = __expf(sg);
            int pos = atomicAdd(&lcur[d >> 8], 1);
            binned[pos] = make_int2(s | ((d & 255) << 16), __float_as_int(w));
        }
    }
}

// ---------------- D4: sortpass + agg + gemm2 fused, one block per bucket.
// Phase S: bucket's edges (mean 4096, cap 8192) sorted by dlow INTO LDS
//          (hist/scan/place — no sortedSW global round-trip).
// Phase G (x4 rounds of 64 nodes): wave wv aggregates nodes wv*4..+3 from the
//          LDS edge lists (R6 TIER gather, hb reads unchanged), elu -> ht LDS.
// Phase M: all 16 waves MFMA the 64-row tile (wave -> row-group wv&3, col-pair
//          (wv>>2)*2) against W2t (L2-direct), write f32 out.
__global__ __launch_bounds__(1024) void sortaggemm_kernel(
    const int2* __restrict__ binned,
    const int* __restrict__ matrixScan,
    const unsigned short* __restrict__ hb,
    const unsigned short* __restrict__ W2t,
    float* __restrict__ out)
{
    __shared__ int2 eb[EBCAP];                  // 64 KB sorted edge buffer
    __shared__ int lhist[256], lscan[256], lcur[256];
    __shared__ unsigned short ht[64][HTP];      // 17.4 KB
    const int tid = threadIdx.x;
    const int b = blockIdx.x;
    const int wv = tid >> 6, lane = tid & 63;

    const int start = matrixScan[b * 256];
    const int end   = (b == NBUCK - 1) ? N_EDGES : matrixScan[(b + 1) * 256];
    const int cnt   = end - start;

    // ---- Phase S: hist over dlow
    if (tid < 256) lhist[tid] = 0;
    __syncthreads();
    for (int i = tid; i < cnt; i += 1024)
        atomicAdd(&lhist[(binned[start + i].x >> 16) & 255], 1);
    __syncthreads();

    int v = 0;
    if (tid < 256) { v = lhist[tid]; lscan[tid] = v; }
    __syncthreads();
    #pragma unroll
    for (int off = 1; off < 256; off <<= 1) {
        int u = 0;
        if (tid < 256 && tid >= off) u = lscan[tid - off];
        __syncthreads();
        if (tid < 256) lscan[tid] += u;
        __syncthreads();
    }
    if (tid < 256) lcur[tid] = lscan[tid] - v;   // exclusive
    __syncthreads();

    for (int i = tid; i < cnt; i += 1024) {
        int2 ent = binned[start + i];
        int dlow = (ent.x >> 16) & 255;
        int pos = atomicAdd(&lcur[dlow], 1);
        eb[pos] = make_int2(ent.x & 0xFFFF, ent.y);
    }
    __syncthreads();

    // ---- Phases G+M: 4 rounds of 64 nodes
    #pragma unroll 1
    for (int r4 = 0; r4 < 4; ++r4) {
        const int base64 = r4 * 64;

        #pragma unroll 1
        for (int s = 0; s < 4; ++s) {
            const int row = wv * 4 + s;          // 0..63
            const int dlow = base64 + row;       // node low byte
            const int beg = lscan[dlow] - lhist[dlow];
            const int deg = lhist[dlow];

            float2 acc = make_float2(0.f, 0.f);
            float wsum = 0.f;

            for (int bb = 0; bb < deg; bb += 64) {
                int c_ = min(64, deg - bb);
                int2 sw = (lane < c_) ? eb[beg + bb + lane] : make_int2(0, 0);
                int j = 0;

#define TIER(T)                                                                 \
                for (; j + T <= c_; j += T) {                                   \
                    unsigned uu[T]; float ww[T];                                \
                    _Pragma("unroll")                                           \
                    for (int k = 0; k < T; ++k) {                               \
                        int s_ = __builtin_amdgcn_readlane(sw.x, j + k);        \
                        uu[k] = *(const unsigned*)(hb + (size_t)s_ * DHID + 2 * lane); \
                    }                                                           \
                    _Pragma("unroll")                                           \
                    for (int k = 0; k < T; ++k)                                 \
                        ww[k] = __uint_as_float(                                \
                            (unsigned)__builtin_amdgcn_readlane(sw.y, j + k));  \
                    _Pragma("unroll")                                           \
                    for (int k = 0; k < T; ++k) {                               \
                        wsum  += ww[k];                                         \
                        acc.x += ww[k] * __uint_as_float(uu[k] << 16);          \
                        acc.y += ww[k] * __uint_as_float(uu[k] & 0xffff0000u);  \
                    }                                                           \
                }

                TIER(16)
                TIER(8)
                TIER(4)
#undef TIER
                for (; j < c_; ++j) {
                    int   sj = __builtin_amdgcn_readlane(sw.x, j);
                    float wj = __uint_as_float((unsigned)__builtin_amdgcn_readlane(sw.y, j));
                    unsigned u = *(const unsigned*)(hb + (size_t)sj * DHID + 2 * lane);
                    acc.x += wj * __uint_as_float(u << 16);
                    acc.y += wj * __uint_as_float(u & 0xffff0000u);
                    wsum  += wj;
                }
            }
            float inv = (deg > 0) ? 1.f / wsum : 0.f;
            float v0 = acc.x * inv, v1 = acc.y * inv;
            float e0 = v0 > 0.f ? v0 : (__expf(v0) - 1.f);
            float e1 = v1 > 0.f ? v1 : (__expf(v1) - 1.f);
            *(unsigned*)&ht[row][2 * lane] =
                (unsigned)f2b(e0) | ((unsigned)f2b(e1) << 16);
        }
        __syncthreads();

        // ---- Phase M: 16 waves cover 64 rows x 8 col-groups (2 per wave)
        {
            const int m = lane & 15, q = lane >> 4;
            const int rg = wv & 3;               // row-group
            const int t0 = (wv >> 2) * 2, t1 = t0 + 1;
            const int arow = rg * 16 + m;

            f32x4 c0 = (f32x4){0.f, 0.f, 0.f, 0.f};
            f32x4 c1 = (f32x4){0.f, 0.f, 0.f, 0.f};
            const short* wb = (const short*)W2t + lane * 8;

            #pragma unroll
            for (int kt = 0; kt < 4; ++kt) {
                bf16x8 a = *(const bf16x8*)&ht[arow][q * 8 + kt * 32];
                bf16x8 b0 = *(const bf16x8*)(wb + (kt * 8 + t0) * 512);
                bf16x8 b1 = *(const bf16x8*)(wb + (kt * 8 + t1) * 512);
                c0 = __builtin_amdgcn_mfma_f32_16x16x32_bf16(a, b0, c0, 0, 0, 0);
                c1 = __builtin_amdgcn_mfma_f32_16x16x32_bf16(a, b1, c1, 0, 0, 0);
            }

            #pragma unroll
            for (int reg = 0; reg < 4; ++reg) {
                int node = (b << 8) + base64 + rg * 16 + q * 4 + reg;
                if (node < N_NODES) {
                    out[(size_t)node * DOUT + t0 * 16 + m] = c0[reg];
                    out[(size_t)node * DOUT + t1 * 16 + m] = c1[reg];
                }
            }
        }
        __syncthreads();   // ht reused next round
    }
}

extern "C" void kernel_launch(void* const* d_in, const int* in_sizes, int n_in,
                              void* d_out, int out_size, void* d_ws, size_t ws_size,
                              hipStream_t stream)
{
    const float* x    = (const float*)d_in[0];
    const int*   ei   = (const int*)d_in[1];
    const float* W1   = (const float*)d_in[2];
    const float* asrc = (const float*)d_in[3];
    const float* adst = (const float*)d_in[4];
    const float* W2   = (const float*)d_in[5];
    float*       out  = (float*)d_out;

    // ---- workspace layout (~20 MB) ----
    char* p = (char*)d_ws;
    unsigned short* hb  = (unsigned short*)p;  p += (size_t)N_NODES * DHID * 2;  // 12.8 MB
    unsigned short* W1t = (unsigned short*)p;  p += (size_t)DHID * DIN * 2;      // 64 KB
    unsigned short* W2t = (unsigned short*)p;  p += (size_t)DOUT * DHID * 2;     // 32 KB
    float* es     = (float*)p;  p += (size_t)N_NODES * 4;
    float* ed     = (float*)p;  p += (size_t)N_NODES * 4;
    int*   blockHistT   = (int*)p; p += (size_t)256 * 256 * 4;                   // 256 KB
    int*   matrixScan   = (int*)p; p += (size_t)NBUCK * 256 * 4;                 // 200 KB
    int2*  binned   = (int2*)p; p += (size_t)N_EDGES * 8;                        // 6.4 MB

    // D1: weight conversion (fragment-ordered) + edge bucket histograms (transposed)
    convW_lhist_kernel<<<48 + BINBLK, 1024, 0, stream>>>(W1, W2, ei, W1t, W2t, blockHistT);

    // D2: gemm1 (+ scan blocks riding in the same dispatch)
    gemm1_scan_kernel<<<G1TILES + NBUCK, 256, 0, stream>>>(
        x, W1t, asrc, adst, blockHistT, hb, es, ed, matrixScan);

    // D3: two-level multi-split (single-writer line ownership)
    binpass_kernel<<<BINBLK, 1024, 0, stream>>>(ei, es, ed, matrixScan, binned);

    // D4: fused sortpass + aggregation + elu + gemm2 (LDS-resident sort)
    sortaggemm_kernel<<<NBUCK, 1024, 0, stream>>>(
        binned, matrixScan, hb, W2t, out);
}

// Round 12
// 181.278 us; speedup vs baseline: 4.3321x; 1.0256x over previous
//
#include <hip/hip_runtime.h>
#include <hip/hip_bf16.h>

#define N_NODES 50000
#define N_EDGES 800000
#define DIN 256
#define DHID 128
#define DOUT 128
#define NBUCK 196     // buckets = dst >> 8
#define BINBLK 256    // histogram partitions (matrixScan row width)
#define EPB 3125      // edges per partition (256*3125 = 800000 exact)
#define G1TILES 391   // ceil(50000/128) gemm1 tiles (4 waves x 32 rows)

typedef __attribute__((ext_vector_type(8))) short bf16x8;
typedef __attribute__((ext_vector_type(4))) float f32x4;

__device__ inline unsigned short f2b(float f) {
    __hip_bfloat16 b = __float2bfloat16(f);
    return *reinterpret_cast<unsigned short*>(&b);
}

// ---------------- D1: weight transpose+cast (fragment-ordered) + edge bucket hist.
// W1t/W2t layout: 16B chunk ((kt*8 + t)*64 + (q*16 + m)) holds bf16 W[k = kt*32+q*8+e][n = t*16+m]
// -> a wave reads 64 consecutive 16B chunks per (kt,t): one fully-coalesced 1KB L2 access.
// blockHistT layout: [partition][bucket] (padded to 256) so scan-side reads coalesce.
__global__ __launch_bounds__(1024) void convW_lhist_kernel(
    const float* __restrict__ W1, const float* __restrict__ W2,
    const int* __restrict__ ei,
    unsigned short* __restrict__ W1t, unsigned short* __restrict__ W2t,
    int* __restrict__ blockHistT)
{
    __shared__ int h[NBUCK];
    const int blk = blockIdx.x;
    const int tid = threadIdx.x;

    if (blk < 48) {                             // 48*1024 = 49152 = 32768 + 16384
        int i = blk * 1024 + tid;
        if (i < DIN * DHID) {                   // W1: n=out channel, k=in channel
            int n = i >> 8, k = i & 255;
            int kt = k >> 5, q = (k >> 3) & 3, e = k & 7;
            int t = n >> 4, m = n & 15;
            W1t[(((kt * 8 + t) * 64) + (q * 16 + m)) * 8 + e] = f2b(W1[k * DHID + n]);
        } else {
            int j = i - DIN * DHID;
            int n = j >> 7, k = j & 127;
            int kt = k >> 5, q = (k >> 3) & 3, e = k & 7;
            int t = n >> 4, m = n & 15;
            W2t[(((kt * 8 + t) * 64) + (q * 16 + m)) * 8 + e] = f2b(W2[k * DOUT + n]);
        }
        return;
    }

    // ---- lhist part: per-partition bucket histogram (bucket = dst >> 8)
    const int b = blk - 48;                     // partition [0, 256)
    if (tid < NBUCK) h[tid] = 0;
    __syncthreads();
    const int base = b * EPB;
    #pragma unroll 1
    for (int it = 0; it < 4; ++it) {
        int e = base + it * 1024 + tid;
        if (e < base + EPB)
            atomicAdd(&h[ei[N_EDGES + e] >> 8], 1);
    }
    __syncthreads();
    if (tid < 256) blockHistT[b * 256 + tid] = (tid < NBUCK) ? h[tid] : 0;  // coalesced
}

// ---------------- D2: gemm1 (+ fused scan blocks): hb = bf16( bf16(x) @ W1 ).
// MFMA 16x16x32, M=32/wave, B direct from L2 (fragment-ordered, no LDS, no barrier).
// Blocks [G1TILES, G1TILES+NBUCK): prefix scan -> matrixScan (coalesced totals).
__global__ __launch_bounds__(256) void gemm1_scan_kernel(
    const float* __restrict__ x,
    const unsigned short* __restrict__ W1t,
    const float* __restrict__ att_src,
    const float* __restrict__ att_dst,
    const int* __restrict__ blockHistT,
    unsigned short* __restrict__ hb,
    float* __restrict__ es,
    float* __restrict__ ed,
    int* __restrict__ matrixScan)
{
    __shared__ int bs[256];
    __shared__ int sc[256];
    const int tid = threadIdx.x;

    if (blockIdx.x >= G1TILES) {
        // ---- scan part ----
        const int b = blockIdx.x - G1TILES;   // bucket [0,196)

        int tot = 0;
        #pragma unroll 4
        for (int p = 0; p < 256; ++p) tot += blockHistT[p * 256 + tid];
        bs[tid] = tot;
        __syncthreads();
        #pragma unroll
        for (int off = 1; off < 256; off <<= 1) {
            int u = (tid >= off) ? bs[tid - off] : 0;
            __syncthreads();
            bs[tid] += u;
            __syncthreads();
        }
        const int base = (b == 0) ? 0 : bs[b - 1];

        int c = blockHistT[tid * 256 + b];    // partition tid's count for bucket b
        sc[tid] = c;
        __syncthreads();
        #pragma unroll
        for (int off = 1; off < 256; off <<= 1) {
            int u = (tid >= off) ? sc[tid - off] : 0;
            __syncthreads();
            sc[tid] += u;
            __syncthreads();
        }
        matrixScan[b * 256 + tid] = base + sc[tid] - c;   // exclusive prefix
        return;
    }

    // ---- gemm1 part: 4 waves x 32 rows = 128 rows per block ----
    const int wave = tid >> 6, lane = tid & 63;
    const int row0 = blockIdx.x * 128 + wave * 32;
    const int m = lane & 15, q = lane >> 4;

    int r0 = row0 + m;
    int r1 = row0 + 16 + m;
    int rc0 = (r0 < N_NODES) ? r0 : 0;
    int rc1 = (r1 < N_NODES) ? r1 : 0;

    f32x4 acc0[8], acc1[8];
    #pragma unroll
    for (int t = 0; t < 8; ++t) {
        acc0[t] = (f32x4){0.f, 0.f, 0.f, 0.f};
        acc1[t] = (f32x4){0.f, 0.f, 0.f, 0.f};
    }

    const float* xr0 = x + (size_t)rc0 * DIN + q * 8;
    const float* xr1 = x + (size_t)rc1 * DIN + q * 8;
    const short* wb  = (const short*)W1t + lane * 8;   // + (kt*8+t)*512 shorts

    #pragma unroll
    for (int kt = 0; kt < 8; ++kt) {
        float4 f0 = *(const float4*)(xr0 + kt * 32);
        float4 f1 = *(const float4*)(xr0 + kt * 32 + 4);
        float4 g0 = *(const float4*)(xr1 + kt * 32);
        float4 g1 = *(const float4*)(xr1 + kt * 32 + 4);
        bf16x8 a0, a1;
        a0[0] = (short)f2b(f0.x); a0[1] = (short)f2b(f0.y);
        a0[2] = (short)f2b(f0.z); a0[3] = (short)f2b(f0.w);
        a0[4] = (short)f2b(f1.x); a0[5] = (short)f2b(f1.y);
        a0[6] = (short)f2b(f1.z); a0[7] = (short)f2b(f1.w);
        a1[0] = (short)f2b(g0.x); a1[1] = (short)f2b(g0.y);
        a1[2] = (short)f2b(g0.z); a1[3] = (short)f2b(g0.w);
        a1[4] = (short)f2b(g1.x); a1[5] = (short)f2b(g1.y);
        a1[6] = (short)f2b(g1.z); a1[7] = (short)f2b(g1.w);
        #pragma unroll
        for (int t = 0; t < 8; ++t) {
            bf16x8 b = *(const bf16x8*)(wb + (kt * 8 + t) * 512);
            acc0[t] = __builtin_amdgcn_mfma_f32_16x16x32_bf16(a0, b, acc0[t], 0, 0, 0);
            acc1[t] = __builtin_amdgcn_mfma_f32_16x16x32_bf16(a1, b, acc1[t], 0, 0, 0);
        }
    }

    #pragma unroll
    for (int reg = 0; reg < 4; ++reg) {
        int ra = row0 + q * 4 + reg;
        int rb = row0 + 16 + q * 4 + reg;
        if (ra < N_NODES) {
            #pragma unroll
            for (int t = 0; t < 8; ++t)
                hb[(size_t)ra * DHID + t * 16 + m] = f2b(acc0[t][reg]);
        }
        if (rb < N_NODES) {
            #pragma unroll
            for (int t = 0; t < 8; ++t)
                hb[(size_t)rb * DHID + t * 16 + m] = f2b(acc1[t][reg]);
        }
    }

    float es0[4] = {0,0,0,0}, ed0[4] = {0,0,0,0};
    float es1[4] = {0,0,0,0}, ed1[4] = {0,0,0,0};
    #pragma unroll
    for (int t = 0; t < 8; ++t) {
        float as = att_src[t * 16 + m];
        float ad = att_dst[t * 16 + m];
        #pragma unroll
        for (int reg = 0; reg < 4; ++reg) {
            es0[reg] += acc0[t][reg] * as;
            ed0[reg] += acc0[t][reg] * ad;
            es1[reg] += acc1[t][reg] * as;
            ed1[reg] += acc1[t][reg] * ad;
        }
    }
    #pragma unroll
    for (int off = 8; off; off >>= 1)
        #pragma unroll
        for (int reg = 0; reg < 4; ++reg) {
            es0[reg] += __shfl_xor(es0[reg], off);
            ed0[reg] += __shfl_xor(ed0[reg], off);
            es1[reg] += __shfl_xor(es1[reg], off);
            ed1[reg] += __shfl_xor(ed1[reg], off);
        }
    if (m == 0) {
        #pragma unroll
        for (int reg = 0; reg < 4; ++reg) {
            int ra = row0 + q * 4 + reg;
            int rb = row0 + 16 + q * 4 + reg;
            if (ra < N_NODES) { es[ra] = es0[reg]; ed[ra] = ed0[reg]; }
            if (rb < N_NODES) { es[rb] = es1[reg]; ed[rb] = ed1[reg]; }
        }
    }
}

// ---------------- D3: binpass — two-level multi-split, per-(partition,bucket) PRIVATE
// ranges (single-writer 64B-line ownership: critical on multi-XCD, proven R5).
__global__ __launch_bounds__(1024) void binpass_kernel(
    const int* __restrict__ ei,
    const float* __restrict__ es,
    const float* __restrict__ ed,
    const int* __restrict__ matrixScan,
    int2* __restrict__ binned)
{
    __shared__ int lcur[NBUCK];
    const int t = threadIdx.x, blk = blockIdx.x;
    if (t < NBUCK) lcur[t] = matrixScan[t * 256 + blk];
    __syncthreads();
    const int base = blk * EPB;
    #pragma unroll 1
    for (int it = 0; it < 4; ++it) {
        int e = base + it * 1024 + t;
        if (e < base + EPB) {
            int s = ei[e];
            int d = ei[N_EDGES + e];
            float a  = es[s] + ed[d];
            float sg = 1.f / (1.f + __expf(-a));
            float w  = __expf(sg);
            int pos = atomicAdd(&lcur[d >> 8], 1);
            binned[pos] = make_int2(s | ((d & 255) << 16), __float_as_int(w));
        }
    }
}

// ---------------- D4: sortpass — one block per bucket (16 waves); hist over dlow,
// scan, place. All writes within the bucket's private range (single-writer lines).
__global__ __launch_bounds__(1024) void sortpass_kernel(
    const int2* __restrict__ binned,
    const int* __restrict__ matrixScan,
    int2* __restrict__ sortedSW,
    int* __restrict__ offset,
    int* __restrict__ count)
{
    __shared__ int lhist[256], lscan[256], lcur[256];
    const int t = threadIdx.x, b = blockIdx.x;
    const int start = matrixScan[b * 256];
    const int end   = (b == NBUCK - 1) ? N_EDGES : matrixScan[(b + 1) * 256];
    const int cnt   = end - start;

    if (t < 256) lhist[t] = 0;
    __syncthreads();
    for (int i = t; i < cnt; i += 1024)
        atomicAdd(&lhist[(binned[start + i].x >> 16) & 255], 1);
    __syncthreads();

    int v = 0;
    if (t < 256) { v = lhist[t]; lscan[t] = v; }
    __syncthreads();
    #pragma unroll
    for (int off = 1; off < 256; off <<= 1) {
        int u = 0;
        if (t < 256 && t >= off) u = lscan[t - off];
        __syncthreads();
        if (t < 256) lscan[t] += u;
        __syncthreads();
    }
    if (t < 256) {
        int excl = lscan[t] - v;
        int node = (b << 8) + t;
        if (node < N_NODES) { offset[node] = start + excl; count[node] = v; }
        lcur[t] = excl;
    }
    __syncthreads();

    for (int i = t; i < cnt; i += 1024) {
        int2 ent = binned[start + i];
        int dlow = (ent.x >> 16) & 255;
        int pos = atomicAdd(&lcur[dlow], 1);
        sortedSW[start + pos] = make_int2(ent.x & 0xFFFF, ent.y);
    }
}

// ---------------- D5: gather-aggregate: one wave/node; tiers 8/4/1;
// fused epilogue: h1b = bf16(elu(acc/wsum)).
__global__ __launch_bounds__(256) void agg_kernel(
    const int2* __restrict__ sortedSW,
    const int* __restrict__ offset,
    const int* __restrict__ count,
    const unsigned short* __restrict__ hb,
    unsigned int* __restrict__ h1b)   // viewed as packed 2x bf16
{
    int node = (blockIdx.x * 256 + threadIdx.x) >> 6;
    int lane = threadIdx.x & 63;
    if (node >= N_NODES) return;

    int beg = offset[node];
    int deg = count[node];

    float2 acc = make_float2(0.f, 0.f);
    float wsum = 0.f;

    for (int base = 0; base < deg; base += 64) {
        int cnt = min(64, deg - base);
        int2 sw = (lane < cnt) ? sortedSW[beg + base + lane] : make_int2(0, 0);
        int j = 0;

#define TIER(T)                                                                 \
        for (; j + T <= cnt; j += T) {                                          \
            unsigned uu[T]; float ww[T];                                        \
            _Pragma("unroll")                                                   \
            for (int k = 0; k < T; ++k) {                                       \
                int s_ = __builtin_amdgcn_readlane(sw.x, j + k);                \
                uu[k] = *(const unsigned*)(hb + (size_t)s_ * DHID + 2 * lane);  \
            }                                                                   \
            _Pragma("unroll")                                                   \
            for (int k = 0; k < T; ++k)                                         \
                ww[k] = __uint_as_float(                                        \
                    (unsigned)__builtin_amdgcn_readlane(sw.y, j + k));          \
            _Pragma("unroll")                                                   \
            for (int k = 0; k < T; ++k) {                                       \
                wsum  += ww[k];                                                 \
                acc.x += ww[k] * __uint_as_float(uu[k] << 16);                  \
                acc.y += ww[k] * __uint_as_float(uu[k] & 0xffff0000u);          \
            }                                                                   \
        }

        TIER(8)
        TIER(4)
#undef TIER
        for (; j < cnt; ++j) {
            int   sj = __builtin_amdgcn_readlane(sw.x, j);
            float wj = __uint_as_float((unsigned)__builtin_amdgcn_readlane(sw.y, j));
            unsigned u = *(const unsigned*)(hb + (size_t)sj * DHID + 2 * lane);
            acc.x += wj * __uint_as_float(u << 16);
            acc.y += wj * __uint_as_float(u & 0xffff0000u);
            wsum  += wj;
        }
    }
    float inv = (deg > 0) ? 1.f / wsum : 0.f;
    float v0 = acc.x * inv, v1 = acc.y * inv;
    float e0 = v0 > 0.f ? v0 : (__expf(v0) - 1.f);
    float e1 = v1 > 0.f ? v1 : (__expf(v1) - 1.f);
    h1b[(size_t)node * (DHID / 2) + lane] =
        (unsigned)f2b(e0) | ((unsigned)f2b(e1) << 16);
}

// ---------------- D6: gemm2: out(f32) = h1b @ W2, MFMA, K=128, M=32/wave, B from L2.
__global__ __launch_bounds__(256) void gemm2_mfma(
    const unsigned short* __restrict__ h1b,
    const unsigned short* __restrict__ W2t,
    float* __restrict__ out)
{
    const int tid = threadIdx.x;
    const int wave = tid >> 6, lane = tid & 63;
    const int row0 = blockIdx.x * 128 + wave * 32;
    const int m = lane & 15, q = lane >> 4;

    int r0 = row0 + m;
    int r1 = row0 + 16 + m;
    int rc0 = (r0 < N_NODES) ? r0 : 0;
    int rc1 = (r1 < N_NODES) ? r1 : 0;

    f32x4 acc0[8], acc1[8];
    #pragma unroll
    for (int t = 0; t < 8; ++t) {
        acc0[t] = (f32x4){0.f, 0.f, 0.f, 0.f};
        acc1[t] = (f32x4){0.f, 0.f, 0.f, 0.f};
    }

    const short* xp0 = (const short*)h1b + (size_t)rc0 * DHID + q * 8;
    const short* xp1 = (const short*)h1b + (size_t)rc1 * DHID + q * 8;
    const short* wb  = (const short*)W2t + lane * 8;

    #pragma unroll
    for (int kt = 0; kt < 4; ++kt) {
        bf16x8 a0 = *(const bf16x8*)(xp0 + kt * 32);
        bf16x8 a1 = *(const bf16x8*)(xp1 + kt * 32);
        #pragma unroll
        for (int t = 0; t < 8; ++t) {
            bf16x8 b = *(const bf16x8*)(wb + (kt * 8 + t) * 512);
            acc0[t] = __builtin_amdgcn_mfma_f32_16x16x32_bf16(a0, b, acc0[t], 0, 0, 0);
            acc1[t] = __builtin_amdgcn_mfma_f32_16x16x32_bf16(a1, b, acc1[t], 0, 0, 0);
        }
    }

    #pragma unroll
    for (int reg = 0; reg < 4; ++reg) {
        int ra = row0 + q * 4 + reg;
        int rb = row0 + 16 + q * 4 + reg;
        if (ra < N_NODES) {
            #pragma unroll
            for (int t = 0; t < 8; ++t)
                out[(size_t)ra * DOUT + t * 16 + m] = acc0[t][reg];
        }
        if (rb < N_NODES) {
            #pragma unroll
            for (int t = 0; t < 8; ++t)
                out[(size_t)rb * DOUT + t * 16 + m] = acc1[t][reg];
        }
    }
}

extern "C" void kernel_launch(void* const* d_in, const int* in_sizes, int n_in,
                              void* d_out, int out_size, void* d_ws, size_t ws_size,
                              hipStream_t stream)
{
    const float* x    = (const float*)d_in[0];
    const int*   ei   = (const int*)d_in[1];
    const float* W1   = (const float*)d_in[2];
    const float* asrc = (const float*)d_in[3];
    const float* adst = (const float*)d_in[4];
    const float* W2   = (const float*)d_in[5];
    float*       out  = (float*)d_out;

    // ---- workspace layout (~40 MB) ----
    char* p = (char*)d_ws;
    unsigned short* hb  = (unsigned short*)p;  p += (size_t)N_NODES * DHID * 2;  // 12.8 MB
    unsigned int*   h1b = (unsigned int*)p;    p += (size_t)N_NODES * DHID * 2;  // 12.8 MB
    unsigned short* W1t = (unsigned short*)p;  p += (size_t)DHID * DIN * 2;      // 64 KB
    unsigned short* W2t = (unsigned short*)p;  p += (size_t)DOUT * DHID * 2;     // 32 KB
    float* es     = (float*)p;  p += (size_t)N_NODES * 4;
    float* ed     = (float*)p;  p += (size_t)N_NODES * 4;
    int*   offset = (int*)p;    p += (size_t)N_NODES * 4;
    int*   count  = (int*)p;    p += (size_t)N_NODES * 4;
    int*   blockHistT   = (int*)p; p += (size_t)256 * 256 * 4;                   // 256 KB
    int*   matrixScan   = (int*)p; p += (size_t)NBUCK * 256 * 4;                 // 200 KB
    int2*  binned   = (int2*)p; p += (size_t)N_EDGES * 8;                        // 6.4 MB
    int2*  sortedSW = (int2*)p; p += (size_t)N_EDGES * 8;                        // 6.4 MB

    // D1: weight conversion (fragment-ordered) + edge bucket histograms (transposed)
    convW_lhist_kernel<<<48 + BINBLK, 1024, 0, stream>>>(W1, W2, ei, W1t, W2t, blockHistT);

    // D2: gemm1 (+ scan blocks riding in the same dispatch, coalesced totals)
    gemm1_scan_kernel<<<G1TILES + NBUCK, 256, 0, stream>>>(
        x, W1t, asrc, adst, blockHistT, hb, es, ed, matrixScan);

    // D3..D6
    binpass_kernel  <<<BINBLK, 1024, 0, stream>>>(ei, es, ed, matrixScan, binned);
    sortpass_kernel <<<NBUCK, 1024, 0, stream>>>(binned, matrixScan, sortedSW, offset, count);
    agg_kernel<<<(N_NODES * 64 + 255) / 256, 256, 0, stream>>>(
        sortedSW, offset, count, hb, h1b);
    gemm2_mfma<<<G1TILES, 256, 0, stream>>>((const unsigned short*)h1b, W2t, out);
}